// Round 13
// baseline (876.818 us; speedup 1.0000x reference)
//
#include <hip/hip_runtime.h>
#include <hip/hip_bf16.h>

#define BATCH 32
#define NN 511
#define FEAT 512
#define NFEAT ((long)32*NN*FEAT)   // 8372224

typedef _Float16 half8 __attribute__((ext_vector_type(8)));
typedef float f32x4 __attribute__((ext_vector_type(4)));

__device__ __forceinline__ float bf2f(unsigned short u){
  union { unsigned int i; float f; } v; v.i = ((unsigned int)u) << 16; return v.f;
}
__device__ __forceinline__ float sigm(float x){ return 1.0f/(1.0f+expf(-x)); }
__device__ __forceinline__ float ldf(const void* p, long i, int f32){
  return f32 ? ((const float*)p)[i] : bf2f(((const unsigned short*)p)[i]);
}

// ---------------- dtype probe: 0 = bf16, 1 = fp32 ----------------
__global__ void detect_kernel(const unsigned short* __restrict__ p, int* __restrict__ flag){
  __shared__ int cnt;
  if (threadIdx.x == 0) cnt = 0;
  __syncthreads();
  int local = 0;
  for (int i = threadIdx.x; i < 4096; i += 256){
    unsigned short u = p[2*i];
    int e = (u >> 7) & 0xFF;
    if (u != 0 && e >= 117 && e <= 133) local++;
  }
  atomicAdd(&cnt, local);
  __syncthreads();
  if (threadIdx.x == 0) *flag = (cnt > 2048) ? 0 : 1;
}

// ---------------- single fused conversion kernel ----------------
__global__ void cvt_all(
    const void* __restrict__ feat, const void* __restrict__ Wiou,
    const void* __restrict__ Wfeiou, const void* __restrict__ Wf,
    const void* __restrict__ Wfef, const void* __restrict__ eh,
    const void* __restrict__ Wln, const void* __restrict__ Wlf,
    const void* __restrict__ biou, const void* __restrict__ bfv,
    _Float16* __restrict__ feat_h, _Float16* __restrict__ Wiou_h,
    _Float16* __restrict__ Wfeiou_h, _Float16* __restrict__ Wf_h,
    _Float16* __restrict__ Wfef_h, _Float16* __restrict__ eh_h,
    _Float16* __restrict__ Wln_h, _Float16* __restrict__ Wlf_h,
    float* __restrict__ biou_f, float* __restrict__ bf_f,
    const int* __restrict__ flag)
{
  long g = ((long)blockIdx.x*256 + threadIdx.x)*8;
  int f32 = *flag;
  const long S1 = NFEAT;            // feat
  const long S2 = S1 + 786432;      // Wiou
  const long S3 = S2 + 786432;      // Wfeiou
  const long S4 = S3 + 262144;      // Wf
  const long S5 = S4 + 262144;      // Wfef
  const long S6 = S5 + 32768;       // eh
  const long S7 = S6 + 524288;      // Wln
  const long S8 = S7 + 524288;      // Wlf  (= 11550720)
  const long S9 = S8 + 1536;        // bias iou (fp32 out)
  const long SA = S9 + 512;         // bias f
  if (g >= SA) return;
  if (g >= S9){
    long o = g - S9;
    for (int q = 0; q < 8; q++) bf_f[o+q] = ldf(bfv, o+q, f32);
    return;
  }
  if (g >= S8){
    long o = g - S8;
    for (int q = 0; q < 8; q++) biou_f[o+q] = ldf(biou, o+q, f32);
    return;
  }
  const void* src; _Float16* dst; long off;
  if      (g < S1){ src=feat;   dst=feat_h;   off=g; }
  else if (g < S2){ src=Wiou;   dst=Wiou_h;   off=g-S1; }
  else if (g < S3){ src=Wfeiou; dst=Wfeiou_h; off=g-S2; }
  else if (g < S4){ src=Wf;     dst=Wf_h;     off=g-S3; }
  else if (g < S5){ src=Wfef;   dst=Wfef_h;   off=g-S4; }
  else if (g < S6){ src=eh;     dst=eh_h;     off=g-S5; }
  else if (g < S7){ src=Wln;    dst=Wln_h;    off=g-S6; }
  else            { src=Wlf;    dst=Wlf_h;    off=g-S7; }
  #pragma unroll
  for (int q = 0; q < 8; q++) dst[off+q] = (_Float16)ldf(src, off+q, f32);
}

// ---------------- e_node/e_forw via MFMA ----------------
__global__ __launch_bounds__(64) void e_mfma(
    const _Float16* __restrict__ eh,
    const _Float16* __restrict__ Wn,
    const _Float16* __restrict__ Wf,
    float* __restrict__ e_node, float* __restrict__ e_forw)
{
  int lane = threadIdx.x;
  int m = lane & 15, quad = lane >> 4;
  int n = blockIdx.x*16 + m;
  const _Float16* wrow = (n < 512) ? (Wn + (long)n*1024) : (Wf + (long)(n-512)*1024);
  f32x4 acc[2] = {};
  for (int ks = 0; ks < 32; ks++){
    int kk = ks*32 + quad*8;
    half8 bfr = *(const half8*)(wrow + kk);
    #pragma unroll
    for (int i = 0; i < 2; i++){
      half8 afr = *(const half8*)(eh + (long)(i*16 + m)*1024 + kk);
      acc[i] = __builtin_amdgcn_mfma_f32_16x16x32_f16(afr, bfr, acc[i], 0, 0, 0);
    }
  }
  float* dst = (n < 512) ? e_node : e_forw;
  int col = (n < 512) ? n : (n - 512);
  #pragma unroll
  for (int i = 0; i < 2; i++)
    #pragma unroll
    for (int reg = 0; reg < 4; reg++){
      int b = i*16 + quad*4 + reg;
      dst[b*FEAT + col] = acc[i][reg];
    }
}

// ---------------- feat2: per-node window softmax ----------------
__global__ void feat2_kernel(const _Float16* __restrict__ feat,
                             const int* __restrict__ finlist,
                             const float* __restrict__ e_node,
                             _Float16* __restrict__ feat2){
  __shared__ float sdots[4];
  int i = blockIdx.x, b = blockIdx.y, tid = threadIdx.x;
  int lane = tid & 63, wv = tid >> 6;
  int s0 = finlist[(b*NN+i)*2+0];
  int e0 = finlist[(b*NN+i)*2+1];
  s0 = min(max(s0, 0), NN-1);
  e0 = min(max(e0, s0), NN-1);
  int w = min(e0 - s0 + 1, 4);
  if (wv < w){
    half8 v = *(const half8*)(feat + ((long)b*NN + s0 + wv)*FEAT + lane*8);
    const float* en = e_node + b*FEAT + lane*8;
    float s = 0.f;
    #pragma unroll
    for (int q = 0; q < 8; q++) s += (float)v[q]*en[q];
    #pragma unroll
    for (int off = 32; off > 0; off >>= 1) s += __shfl_down(s, off, 64);
    if (lane == 0) sdots[wv] = s;
  }
  __syncthreads();
  float sc[4]; float mx = -1e30f;
  #pragma unroll
  for (int q = 0; q < 4; q++){
    sc[q] = (q < w) ? sdots[q] : -1e30f;
    mx = fmaxf(mx, sc[q]);
  }
  float p[4]; float den = 0.f;
  #pragma unroll
  for (int q = 0; q < 4; q++){ p[q] = (q < w) ? expf(sc[q]-mx) : 0.f; den += p[q]; }
  float inv = 1.f/den;
  #pragma unroll
  for (int q = 0; q < 4; q++) p[q] *= inv;
  #pragma unroll
  for (int e = 0; e < 2; e++){
    int f = tid + e*256;
    float acc = 0.f;
    for (int q = 0; q < w; q++)
      acc += p[q]*(float)feat[((long)b*NN+s0+q)*FEAT + f];
    feat2[((long)b*NN+i)*FEAT+f] = (_Float16)acc;
  }
}

// ---------------- 128x128 LDS-tiled MFMA GEMM, conflict-free swizzle -----------------
// grid: bx = row tile (fast), by = col-group. by<12: iou (M=32P,N=1536); by>=12 (levels):
// f gates (M=64P, N=512, cols (by-12)*128).
// LDS layout (per buffer): slot(r,q) at halfs offset (q*128 + r)*8 -> reader quarter-wave
// sweeps consecutive 16B slots (2-way alias = free); writer likewise. Banks verified.
// K-loop: double-buffered, one barrier per K-step.
__global__ __launch_bounds__(256) void gemm_tile(
    int leaf, int P, int lp,
    const _Float16* __restrict__ feat2, const _Float16* __restrict__ hbuf,
    const _Float16* __restrict__ Wiou, const _Float16* __restrict__ Wfeiou,
    const _Float16* __restrict__ Wf,   const _Float16* __restrict__ Wfef,
    const float* __restrict__ biou, const float* __restrict__ bfv,
    _Float16* __restrict__ iou_out, _Float16* __restrict__ f_out)
{
  __shared__ __align__(16) _Float16 sA[2][4096];  // 4 quads x 128 rows x 8 halfs = 8 KB
  __shared__ __align__(16) _Float16 sB[2][4096];
  int tid = threadIdx.x;
  int lane = tid & 63, w = tid >> 6;
  int w0 = w & 1, w1 = w >> 1;
  int m = lane & 15, quad = lane >> 4;
  int cgy = blockIdx.y;
  bool isF = (!leaf) && (cgy >= 12);
  int Mtot    = isF ? (P << 6) : (P << 5);
  int colbase = isF ? (cgy - 12)*128 : cgy*128;
  int rowbase = blockIdx.x*128;
  if (rowbase >= Mtot) return;
  int p0 = P - 1, c0 = 2*P - 1;

  // staging: thread handles chunks c = tid, tid+256 ; q = c>>7, r = c&127
  int st_q[2], st_r[2], st_off[2];
  #pragma unroll
  for (int u = 0; u < 2; u++){
    int c = tid + u*256;
    st_q[u] = c >> 7; st_r[u] = c & 127;
    st_off[u] = (st_q[u]*128 + st_r[u])*8;
  }

  bool dual = false;
  const _Float16 *aptr[2], *aptr2[2], *bptr[2];
  auto setup = [&](int phase){
    const _Float16* W = isF ? (phase ? Wfef : Wf)
                            : ((phase || leaf) ? Wfeiou : Wiou);
    dual = (!leaf && !isF && phase == 0);
    #pragma unroll
    for (int u = 0; u < 2; u++){
      int r = rowbase + st_r[u];
      if (r > Mtot-1) r = Mtot-1;
      const _Float16* base;
      if (leaf){
        int b = r >> lp, p = r & (P-1);
        base = feat2 + ((long)b*NN + 255 + p)*FEAT;
      } else if (!isF){
        int b = r >> lp, p = r & (P-1);
        if (phase == 0) base = hbuf + ((long)b*NN + c0 + 2*p)*FEAT;
        else            base = feat2 + ((long)b*NN + p0 + p)*FEAT;
      } else {
        int b = r >> (lp+1), q = r & (2*P-1);
        if (phase == 0) base = hbuf + ((long)b*NN + c0 + q)*FEAT;
        else            base = feat2 + ((long)b*NN + p0 + (q>>1))*FEAT;
      }
      aptr[u]  = base + st_q[u]*8;
      aptr2[u] = aptr[u] + FEAT;   // second child (dual only)
      bptr[u]  = W + (long)(colbase + st_r[u])*FEAT + st_q[u]*8;
    }
  };

  f32x4 acc[4][4] = {};
  half8 ra[2], ra2[2], rb[2];

  int totK = leaf ? 16 : 32;
  setup(0);
  #pragma unroll
  for (int u = 0; u < 2; u++){
    ra[u] = *(const half8*)(aptr[u]);
    if (dual) ra2[u] = *(const half8*)(aptr2[u]);
    rb[u] = *(const half8*)(bptr[u]);
  }
  #pragma unroll
  for (int u = 0; u < 2; u++){
    half8 v = ra[u];
    if (dual) v = v + ra2[u];
    *(half8*)(&sA[0][st_off[u]]) = v;
    *(half8*)(&sB[0][st_off[u]]) = rb[u];
  }
  __syncthreads();

  for (int ks = 0; ks < totK; ks++){
    int cur = ks & 1;
    bool more = (ks + 1 < totK);
    if (more){
      int kn = ks + 1;
      if (!leaf && kn == 16) setup(1);
      long kk = (long)(kn & 15)*32;
      #pragma unroll
      for (int u = 0; u < 2; u++){
        ra[u] = *(const half8*)(aptr[u] + kk);
        if (dual) ra2[u] = *(const half8*)(aptr2[u] + kk);
        rb[u] = *(const half8*)(bptr[u] + kk);
      }
    }
    half8 afr[4], bfr[4];
    #pragma unroll
    for (int i = 0; i < 4; i++)
      afr[i] = *(const half8*)(&sA[cur][(quad*128 + w0*64 + i*16 + m)*8]);
    #pragma unroll
    for (int j = 0; j < 4; j++)
      bfr[j] = *(const half8*)(&sB[cur][(quad*128 + w1*64 + j*16 + m)*8]);
    #pragma unroll
    for (int i = 0; i < 4; i++)
      #pragma unroll
      for (int j = 0; j < 4; j++)
        acc[i][j] = __builtin_amdgcn_mfma_f32_16x16x32_f16(afr[i], bfr[j], acc[i][j], 0, 0, 0);
    if (more){
      #pragma unroll
      for (int u = 0; u < 2; u++){
        half8 v = ra[u];
        if (dual) v = v + ra2[u];
        *(half8*)(&sA[cur^1][st_off[u]]) = v;
        *(half8*)(&sB[cur^1][st_off[u]]) = rb[u];
      }
      __syncthreads();
    }
  }

  const float* bias = isF ? bfv : biou;
  #pragma unroll
  for (int j = 0; j < 4; j++){
    int nl = w1*64 + j*16 + m;
    float bs = bias[colbase + nl];
    #pragma unroll
    for (int i = 0; i < 4; i++){
      #pragma unroll
      for (int reg = 0; reg < 4; reg++){
        int r = rowbase + w0*64 + i*16 + quad*4 + reg;
        if (r < Mtot){
          _Float16 val = (_Float16)(acc[i][j][reg] + bs);
          if (!isF) iou_out[(long)r*1536 + colbase + nl] = val;
          else      f_out[(long)r*512  + colbase + nl] = val;
        }
      }
    }
  }
}

// ---------------- level-0 pointwise (leaves) ----------------
__global__ void pw_leaf(const _Float16* __restrict__ iou, float* __restrict__ c,
                        _Float16* __restrict__ h){
  int r = blockIdx.x, b = blockIdx.y, t = threadIdx.x;
  const _Float16* row = iou + ((long)b*256 + r)*1536;
  long off = ((long)b*NN + 255 + r)*FEAT;
  #pragma unroll
  for (int e = 0; e < 2; e++){
    int f = t + e*256;
    float ig = (float)row[f], og = (float)row[FEAT+f], ug = (float)row[2*FEAT+f];
    float cn = sigm(ig)*fmaxf(ug, 0.f);
    float hn = sigm(og)*tanhf(cn);
    c[off+f] = cn;
    h[off+f] = (_Float16)hn;
  }
}

// ---------------- level-n pointwise ----------------
__global__ void pw_level(const _Float16* __restrict__ iou, const _Float16* __restrict__ fbuf,
                         float* __restrict__ c, _Float16* __restrict__ h,
                         int P, int p0, int c0){
  int r = blockIdx.x, b = blockIdx.y, t = threadIdx.x;
  const _Float16* row = iou + ((long)b*P + r)*1536;
  const _Float16* fl = fbuf + ((long)b*2*P + 2*r)*FEAT;
  const _Float16* fr = fl + FEAT;
  long cl = ((long)b*NN + c0 + 2*r)*FEAT;
  long cr = cl + FEAT;
  long po = ((long)b*NN + p0 + r)*FEAT;
  #pragma unroll
  for (int e = 0; e < 2; e++){
    int f = t + e*256;
    float csum = sigm((float)fl[f])*c[cl+f] + sigm((float)fr[f])*c[cr+f];
    float cn = sigm((float)row[f])*fmaxf((float)row[2*FEAT+f], 0.f) + csum;
    float hn = sigm((float)row[FEAT+f])*tanhf(cn);
    c[po+f] = cn;
    h[po+f] = (_Float16)hn;
  }
}

// ---------------- logits[b,i] = dot(h[b,i,:], e_forw[b,:]) ----------------
__global__ void logits_kernel(const _Float16* __restrict__ h,
                              const float* __restrict__ e_forw,
                              float* __restrict__ logits){
  int b = blockIdx.y;
  int wave = threadIdx.x >> 6, lane = threadIdx.x & 63;
  int i = blockIdx.x*4 + wave;
  if (i >= NN) return;
  half8 hv = *(const half8*)(h + ((long)b*NN+i)*FEAT + lane*8);
  const float* ef = e_forw + b*FEAT + lane*8;
  float s = 0.f;
  #pragma unroll
  for (int q = 0; q < 8; q++) s += (float)hv[q]*ef[q];
  #pragma unroll
  for (int off = 32; off > 0; off >>= 1) s += __shfl_down(s, off, 64);
  if (lane == 0) logits[b*NN+i] = s;
}

// ---------------- softmax over nodes + weighted sum -> fp32 out ----------------
__global__ void out_kernel(const _Float16* __restrict__ h,
                           const float* __restrict__ logits,
                           float* __restrict__ out){
  __shared__ float sprob[NN+1];
  __shared__ float red[128];
  int b = blockIdx.x, yc = blockIdx.y, t = threadIdx.x;
  float mx = -1e30f;
  for (int i = t; i < NN; i += 128) mx = fmaxf(mx, logits[b*NN+i]);
  red[t] = mx; __syncthreads();
  for (int s = 64; s > 0; s >>= 1){ if (t < s) red[t] = fmaxf(red[t], red[t+s]); __syncthreads(); }
  mx = red[0]; __syncthreads();
  float sum = 0.f;
  for (int i = t; i < NN; i += 128){ float p = expf(logits[b*NN+i]-mx); sprob[i] = p; sum += p; }
  red[t] = sum; __syncthreads();
  for (int s = 64; s > 0; s >>= 1){ if (t < s) red[t] += red[t+s]; __syncthreads(); }
  float inv = 1.f/red[0];
  __syncthreads();
  int f = yc*128 + t;
  float acc = 0.f;
  for (int i = 0; i < NN; i++) acc += sprob[i]*(float)h[((long)b*NN+i)*FEAT+f];
  out[b*FEAT+f] = acc*inv;   // OUTPUT IS FP32
}

extern "C" void kernel_launch(void* const* d_in, const int* in_sizes, int n_in,
                              void* d_out, int out_size, void* d_ws, size_t ws_size,
                              hipStream_t stream){
  (void)in_sizes; (void)n_in; (void)out_size; (void)ws_size;
  const void* feat_raw   = d_in[0];
  const int*  finlist    = (const int*)d_in[4];
  const void* eh_raw     = d_in[5];
  const void* Wln_raw    = d_in[6];
  const void* Wlf_raw    = d_in[7];
  const void* Wiou_raw   = d_in[8];
  const void* Wfeiou_raw = d_in[9];
  const void* bfeiou_raw = d_in[10];
  const void* Wf_raw     = d_in[11];
  const void* Wfef_raw   = d_in[12];
  const void* bfef_raw   = d_in[13];

  char* ws = (char*)d_ws;
  size_t off = 0;
  auto alloc = [&](size_t bytes)->char*{
    char* p = ws + off; off += (bytes + 255) & ~(size_t)255; return p;
  };
  int*      flag     = (int*)alloc(256);
  _Float16* feat_h   = (_Float16*)alloc((size_t)NFEAT*2);
  _Float16* Wiou_h   = (_Float16*)alloc((size_t)1536*512*2);
  _Float16* Wfeiou_h = (_Float16*)alloc((size_t)1536*512*2);
  _Float16* Wf_h     = (_Float16*)alloc((size_t)512*512*2);
  _Float16* Wfef_h   = (_Float16*)alloc((size_t)512*512*2);
  _Float16* eh_h     = (_Float16*)alloc((size_t)32*1024*2);
  _Float16* Wln_h    = (_Float16*)alloc((size_t)512*1024*2);
  _Float16* Wlf_h    = (_Float16*)alloc((size_t)512*1024*2);
  float*    bfeiou_f = (float*)alloc((size_t)1536*4);
  float*    bfef_f   = (float*)alloc((size_t)512*4);
  float*    e_node   = (float*)alloc((size_t)32*512*4);
  float*    e_forw   = (float*)alloc((size_t)32*512*4);
  _Float16* feat2    = (_Float16*)alloc((size_t)NFEAT*2);
  _Float16* h_half   = (_Float16*)alloc((size_t)NFEAT*2);
  float*    c_buf    = (float*)alloc((size_t)NFEAT*4);
  _Float16* iou_buf  = (_Float16*)alloc((size_t)32*256*1536*2);
  _Float16* f_buf    = (_Float16*)alloc((size_t)32*256*512*2);
  float*    logits   = (float*)alloc((size_t)32*NN*4);

  detect_kernel<<<dim3(1), 256, 0, stream>>>((const unsigned short*)feat_raw, flag);

  cvt_all<<<dim3(5641), 256, 0, stream>>>(
      feat_raw, Wiou_raw, Wfeiou_raw, Wf_raw, Wfef_raw, eh_raw, Wln_raw, Wlf_raw,
      bfeiou_raw, bfef_raw,
      feat_h, Wiou_h, Wfeiou_h, Wf_h, Wfef_h, eh_h, Wln_h, Wlf_h,
      bfeiou_f, bfef_f, flag);

  e_mfma<<<dim3(64), 64, 0, stream>>>(eh_h, Wln_h, Wlf_h, e_node, e_forw);
  feat2_kernel<<<dim3(NN,32), 256, 0, stream>>>(feat_h, finlist, e_node, feat2);

  // level 0: leaves: M = 8192 rows -> 64 row tiles x 12 col groups
  gemm_tile<<<dim3(64, 12), 256, 0, stream>>>(1, 256, 8,
      feat2, h_half, Wiou_h, Wfeiou_h, Wf_h, Wfef_h,
      bfeiou_f, bfef_f, iou_buf, f_buf);
  pw_leaf<<<dim3(256,32), 256, 0, stream>>>(iou_buf, c_buf, h_half);

  for (int n = 1; n <= 8; n++){
    int P = 1 << (8-n);
    int lp = 8 - n;
    int p0 = P - 1, c0 = 2*P - 1;
    int gx = (64*P + 127)/128;           // max of iou/f row tiles (f is larger)
    gemm_tile<<<dim3(gx, 16), 256, 0, stream>>>(0, P, lp,
        feat2, h_half, Wiou_h, Wfeiou_h, Wf_h, Wfef_h, bfeiou_f, bfef_f, iou_buf, f_buf);
    pw_level<<<dim3(P,32), 256, 0, stream>>>(iou_buf, f_buf, c_buf, h_half, P, p0, c0);
  }

  logits_kernel<<<dim3(128,32), 256, 0, stream>>>(h_half, e_forw, logits);
  out_kernel<<<dim3(32,4), 128, 0, stream>>>(h_half, logits, (float*)d_out);
}

// Round 14
// 722.413 us; speedup vs baseline: 1.2137x; 1.2137x over previous
//
#include <hip/hip_runtime.h>
#include <hip/hip_bf16.h>

#define BATCH 32
#define NN 511
#define FEAT 512
#define NFEAT ((long)32*NN*FEAT)   // 8372224

typedef _Float16 half8 __attribute__((ext_vector_type(8)));
typedef float f32x4 __attribute__((ext_vector_type(4)));

__device__ __forceinline__ float bf2f(unsigned short u){
  union { unsigned int i; float f; } v; v.i = ((unsigned int)u) << 16; return v.f;
}
__device__ __forceinline__ float sigm(float x){ return 1.0f/(1.0f+expf(-x)); }
__device__ __forceinline__ float ldf(const void* p, long i, int f32){
  return f32 ? ((const float*)p)[i] : bf2f(((const unsigned short*)p)[i]);
}

// ---------------- dtype probe: 0 = bf16, 1 = fp32 ----------------
__global__ void detect_kernel(const unsigned short* __restrict__ p, int* __restrict__ flag){
  __shared__ int cnt;
  if (threadIdx.x == 0) cnt = 0;
  __syncthreads();
  int local = 0;
  for (int i = threadIdx.x; i < 4096; i += 256){
    unsigned short u = p[2*i];
    int e = (u >> 7) & 0xFF;
    if (u != 0 && e >= 117 && e <= 133) local++;
  }
  atomicAdd(&cnt, local);
  __syncthreads();
  if (threadIdx.x == 0) *flag = (cnt > 2048) ? 0 : 1;
}

// ---------------- single fused conversion kernel ----------------
__global__ void cvt_all(
    const void* __restrict__ feat, const void* __restrict__ Wiou,
    const void* __restrict__ Wfeiou, const void* __restrict__ Wf,
    const void* __restrict__ Wfef, const void* __restrict__ eh,
    const void* __restrict__ Wln, const void* __restrict__ Wlf,
    const void* __restrict__ biou, const void* __restrict__ bfv,
    _Float16* __restrict__ feat_h, _Float16* __restrict__ Wiou_h,
    _Float16* __restrict__ Wfeiou_h, _Float16* __restrict__ Wf_h,
    _Float16* __restrict__ Wfef_h, _Float16* __restrict__ eh_h,
    _Float16* __restrict__ Wln_h, _Float16* __restrict__ Wlf_h,
    float* __restrict__ biou_f, float* __restrict__ bf_f,
    const int* __restrict__ flag)
{
  long g = ((long)blockIdx.x*256 + threadIdx.x)*8;
  int f32 = *flag;
  const long S1 = NFEAT;            // feat
  const long S2 = S1 + 786432;      // Wiou
  const long S3 = S2 + 786432;      // Wfeiou
  const long S4 = S3 + 262144;      // Wf
  const long S5 = S4 + 262144;      // Wfef
  const long S6 = S5 + 32768;       // eh
  const long S7 = S6 + 524288;      // Wln
  const long S8 = S7 + 524288;      // Wlf  (= 11550720)
  const long S9 = S8 + 1536;        // bias iou (fp32 out)
  const long SA = S9 + 512;         // bias f
  if (g >= SA) return;
  if (g >= S9){
    long o = g - S9;
    for (int q = 0; q < 8; q++) bf_f[o+q] = ldf(bfv, o+q, f32);
    return;
  }
  if (g >= S8){
    long o = g - S8;
    for (int q = 0; q < 8; q++) biou_f[o+q] = ldf(biou, o+q, f32);
    return;
  }
  const void* src; _Float16* dst; long off;
  if      (g < S1){ src=feat;   dst=feat_h;   off=g; }
  else if (g < S2){ src=Wiou;   dst=Wiou_h;   off=g-S1; }
  else if (g < S3){ src=Wfeiou; dst=Wfeiou_h; off=g-S2; }
  else if (g < S4){ src=Wf;     dst=Wf_h;     off=g-S3; }
  else if (g < S5){ src=Wfef;   dst=Wfef_h;   off=g-S4; }
  else if (g < S6){ src=eh;     dst=eh_h;     off=g-S5; }
  else if (g < S7){ src=Wln;    dst=Wln_h;    off=g-S6; }
  else            { src=Wlf;    dst=Wlf_h;    off=g-S7; }
  #pragma unroll
  for (int q = 0; q < 8; q++) dst[off+q] = (_Float16)ldf(src, off+q, f32);
}

// ---------------- e_node/e_forw via MFMA ----------------
__global__ __launch_bounds__(64) void e_mfma(
    const _Float16* __restrict__ eh,
    const _Float16* __restrict__ Wn,
    const _Float16* __restrict__ Wf,
    float* __restrict__ e_node, float* __restrict__ e_forw)
{
  int lane = threadIdx.x;
  int m = lane & 15, quad = lane >> 4;
  int n = blockIdx.x*16 + m;
  const _Float16* wrow = (n < 512) ? (Wn + (long)n*1024) : (Wf + (long)(n-512)*1024);
  f32x4 acc[2] = {};
  for (int ks = 0; ks < 32; ks++){
    int kk = ks*32 + quad*8;
    half8 bfr = *(const half8*)(wrow + kk);
    #pragma unroll
    for (int i = 0; i < 2; i++){
      half8 afr = *(const half8*)(eh + (long)(i*16 + m)*1024 + kk);
      acc[i] = __builtin_amdgcn_mfma_f32_16x16x32_f16(afr, bfr, acc[i], 0, 0, 0);
    }
  }
  float* dst = (n < 512) ? e_node : e_forw;
  int col = (n < 512) ? n : (n - 512);
  #pragma unroll
  for (int i = 0; i < 2; i++)
    #pragma unroll
    for (int reg = 0; reg < 4; reg++){
      int b = i*16 + quad*4 + reg;
      dst[b*FEAT + col] = acc[i][reg];
    }
}

// ---------------- feat2: per-node window softmax ----------------
__global__ void feat2_kernel(const _Float16* __restrict__ feat,
                             const int* __restrict__ finlist,
                             const float* __restrict__ e_node,
                             _Float16* __restrict__ feat2){
  __shared__ float sdots[4];
  int i = blockIdx.x, b = blockIdx.y, tid = threadIdx.x;
  int lane = tid & 63, wv = tid >> 6;
  int s0 = finlist[(b*NN+i)*2+0];
  int e0 = finlist[(b*NN+i)*2+1];
  s0 = min(max(s0, 0), NN-1);
  e0 = min(max(e0, s0), NN-1);
  int w = min(e0 - s0 + 1, 4);
  if (wv < w){
    half8 v = *(const half8*)(feat + ((long)b*NN + s0 + wv)*FEAT + lane*8);
    const float* en = e_node + b*FEAT + lane*8;
    float s = 0.f;
    #pragma unroll
    for (int q = 0; q < 8; q++) s += (float)v[q]*en[q];
    #pragma unroll
    for (int off = 32; off > 0; off >>= 1) s += __shfl_down(s, off, 64);
    if (lane == 0) sdots[wv] = s;
  }
  __syncthreads();
  float sc[4]; float mx = -1e30f;
  #pragma unroll
  for (int q = 0; q < 4; q++){
    sc[q] = (q < w) ? sdots[q] : -1e30f;
    mx = fmaxf(mx, sc[q]);
  }
  float p[4]; float den = 0.f;
  #pragma unroll
  for (int q = 0; q < 4; q++){ p[q] = (q < w) ? expf(sc[q]-mx) : 0.f; den += p[q]; }
  float inv = 1.f/den;
  #pragma unroll
  for (int q = 0; q < 4; q++) p[q] *= inv;
  #pragma unroll
  for (int e = 0; e < 2; e++){
    int f = tid + e*256;
    float acc = 0.f;
    for (int q = 0; q < w; q++)
      acc += p[q]*(float)feat[((long)b*NN+s0+q)*FEAT + f];
    feat2[((long)b*NN+i)*FEAT+f] = (_Float16)acc;
  }
}

// ---------------- PRECOMPUTE GEMM: fe_iou (all nodes) + fe_f (all parents) -----------
// cg<24 : fe_iou[b,node] = feat2[b,node] @ Wfeiou^T + biou   (M = 32*512 padded)
// 24..31: fe_f[b,p]      = feat2[b,p]    @ Wfef^T   + bf     (M = 32*256 padded)
// One wave per 64x64 tile, depth-1 register pipeline (R11 body).
__global__ __launch_bounds__(64) void gemm_pre(
    const _Float16* __restrict__ feat2,
    const _Float16* __restrict__ Wfeiou, const _Float16* __restrict__ Wfef,
    const float* __restrict__ biou, const float* __restrict__ bfv,
    _Float16* __restrict__ fe_iou, _Float16* __restrict__ fe_f)
{
  int lane = threadIdx.x;
  int m = lane & 15, quad = lane >> 4;
  int cg = blockIdx.y;
  bool isF = (cg >= 24);
  int Mtot = isF ? 8192 : 16384;
  int rowbase = blockIdx.x*64;
  if (rowbase >= Mtot) return;
  int colbase = isF ? (cg-24)*64 : cg*64;
  const _Float16* W = isF ? Wfef : Wfeiou;

  f32x4 acc[4][4] = {};
  const _Float16* ap[4];
  const _Float16* wp[4];
  #pragma unroll
  for (int i = 0; i < 4; i++){
    int r = rowbase + i*16 + m;
    if (r > Mtot-1) r = Mtot-1;
    int b, node;
    if (!isF){ b = r >> 9; node = r & 511; if (node > 510) node = 510; }
    else     { b = r >> 8; node = r & 255; if (node > 254) node = 254; }
    ap[i] = feat2 + ((long)b*NN + node)*FEAT + quad*8;
    wp[i] = W + (long)(colbase + i*16 + m)*FEAT + quad*8;
  }

  half8 ca[4], cb[4];
  #pragma unroll
  for (int i = 0; i < 4; i++){
    ca[i] = *(const half8*)(ap[i]);
    cb[i] = *(const half8*)(wp[i]);
  }
  #pragma unroll 1
  for (int ks = 0; ks < 16; ++ks){
    half8 na[4], nb[4];
    bool more = (ks < 15);
    if (more){
      long kk = (long)(ks+1)*32;
      #pragma unroll
      for (int i = 0; i < 4; i++){
        na[i] = *(const half8*)(ap[i] + kk);
        nb[i] = *(const half8*)(wp[i] + kk);
      }
    }
    #pragma unroll
    for (int i = 0; i < 4; i++)
      #pragma unroll
      for (int j = 0; j < 4; j++)
        acc[i][j] = __builtin_amdgcn_mfma_f32_16x16x32_f16(ca[i], cb[j], acc[i][j], 0, 0, 0);
    if (more){
      #pragma unroll
      for (int i = 0; i < 4; i++){ ca[i] = na[i]; cb[i] = nb[i]; }
    }
  }

  const float* bias = isF ? bfv : biou;
  #pragma unroll
  for (int j = 0; j < 4; j++){
    int n = colbase + j*16 + m;
    float bs = bias[n];
    #pragma unroll
    for (int i = 0; i < 4; i++){
      #pragma unroll
      for (int reg = 0; reg < 4; reg++){
        int r = rowbase + i*16 + quad*4 + reg;
        if (r < Mtot){
          if (!isF){
            int b = r >> 9, node = r & 511;
            if (node <= 510)
              fe_iou[((long)b*NN + node)*1536 + n] = (_Float16)(acc[i][j][reg] + bs);
          } else {
            int b = r >> 8, p = r & 255;
            if (p <= 254)
              fe_f[((long)b*255 + p)*512 + n] = (_Float16)(acc[i][j][reg] + bs);
          }
        }
      }
    }
  }
}

// ---------------- per-level GEMM: h-dependent part only, K=512 single phase ----------
// cg<24 : iou: A = h[c0+2p]+h[c0+2p+1], W=Wiou; epilogue: fe_iou[b,p0+p] += acc (in-place)
// 24..31: f  : rows q over both children (M=64P): A = h[c0+q], W=Wf;
//          epilogue: f_out[r*512+n] = acc + fe_f[b, p0+(q>>1)]
__global__ __launch_bounds__(64) void gemm_lvl(
    int P, int lp,
    const _Float16* __restrict__ hbuf,
    const _Float16* __restrict__ Wiou, const _Float16* __restrict__ Wf,
    _Float16* __restrict__ fe_iou, const _Float16* __restrict__ fe_f,
    _Float16* __restrict__ f_out)
{
  int lane = threadIdx.x;
  int m = lane & 15, quad = lane >> 4;
  int cg = blockIdx.y;
  bool isF = (cg >= 24);
  int Mtot = isF ? (P << 6) : (P << 5);
  int rowbase = blockIdx.x*64;
  if (rowbase >= Mtot) return;
  int colbase = isF ? (cg-24)*64 : cg*64;
  const _Float16* W = isF ? Wf : Wiou;
  int p0 = P - 1, c0 = 2*P - 1;

  f32x4 acc[4][4] = {};
  const _Float16* ap[4];
  const _Float16* wp[4];
  bool dual = !isF;
  #pragma unroll
  for (int i = 0; i < 4; i++){
    int r = rowbase + i*16 + m;
    if (r > Mtot-1) r = Mtot-1;
    int b, node;
    if (!isF){ b = r >> lp; int p = r & (P-1); node = c0 + 2*p; }
    else     { b = r >> (lp+1); int q = r & (2*P-1); node = c0 + q; }
    ap[i] = hbuf + ((long)b*NN + node)*FEAT + quad*8;
    wp[i] = W + (long)(colbase + i*16 + m)*FEAT + quad*8;
  }

  half8 ca[4], cb[4];
  #pragma unroll
  for (int i = 0; i < 4; i++){
    half8 v = *(const half8*)(ap[i]);
    if (dual) v = v + *(const half8*)(ap[i] + FEAT);
    ca[i] = v;
    cb[i] = *(const half8*)(wp[i]);
  }
  #pragma unroll 1
  for (int ks = 0; ks < 16; ++ks){
    half8 na[4], nb[4];
    bool more = (ks < 15);
    if (more){
      long kk = (long)(ks+1)*32;
      #pragma unroll
      for (int i = 0; i < 4; i++){
        half8 v = *(const half8*)(ap[i] + kk);
        if (dual) v = v + *(const half8*)(ap[i] + FEAT + kk);
        na[i] = v;
        nb[i] = *(const half8*)(wp[i] + kk);
      }
    }
    #pragma unroll
    for (int i = 0; i < 4; i++)
      #pragma unroll
      for (int j = 0; j < 4; j++)
        acc[i][j] = __builtin_amdgcn_mfma_f32_16x16x32_f16(ca[i], cb[j], acc[i][j], 0, 0, 0);
    if (more){
      #pragma unroll
      for (int i = 0; i < 4; i++){ ca[i] = na[i]; cb[i] = nb[i]; }
    }
  }

  #pragma unroll
  for (int j = 0; j < 4; j++){
    int n = colbase + j*16 + m;
    #pragma unroll
    for (int i = 0; i < 4; i++){
      #pragma unroll
      for (int reg = 0; reg < 4; reg++){
        int r = rowbase + i*16 + quad*4 + reg;
        if (r < Mtot){
          if (!isF){
            int b = r >> lp, p = r & (P-1);
            long addr = ((long)b*NN + p0 + p)*1536 + n;
            fe_iou[addr] = (_Float16)(acc[i][j][reg] + (float)fe_iou[addr]);
          } else {
            int b = r >> (lp+1), q = r & (2*P-1);
            float fe = (float)fe_f[((long)b*255 + p0 + (q>>1))*512 + n];
            f_out[(long)r*512 + n] = (_Float16)(acc[i][j][reg] + fe);
          }
        }
      }
    }
  }
}

// ---------------- level-0 pointwise (leaves): iou = fe_iou directly ----------------
__global__ void pw_leaf(const _Float16* __restrict__ fe_iou, float* __restrict__ c,
                        _Float16* __restrict__ h){
  int r = blockIdx.x, b = blockIdx.y, t = threadIdx.x;
  const _Float16* row = fe_iou + ((long)b*NN + 255 + r)*1536;
  long off = ((long)b*NN + 255 + r)*FEAT;
  #pragma unroll
  for (int e = 0; e < 2; e++){
    int f = t + e*256;
    float ig = (float)row[f], og = (float)row[FEAT+f], ug = (float)row[2*FEAT+f];
    float cn = sigm(ig)*fmaxf(ug, 0.f);
    float hn = sigm(og)*tanhf(cn);
    c[off+f] = cn;
    h[off+f] = (_Float16)hn;
  }
}

// ---------------- level-n pointwise: iou from fe_iou (node-indexed) ----------------
__global__ void pw_level(const _Float16* __restrict__ fe_iou, const _Float16* __restrict__ fbuf,
                         float* __restrict__ c, _Float16* __restrict__ h,
                         int P, int p0, int c0){
  int r = blockIdx.x, b = blockIdx.y, t = threadIdx.x;
  const _Float16* row = fe_iou + ((long)b*NN + p0 + r)*1536;
  const _Float16* fl = fbuf + ((long)b*2*P + 2*r)*FEAT;
  const _Float16* fr = fl + FEAT;
  long cl = ((long)b*NN + c0 + 2*r)*FEAT;
  long cr = cl + FEAT;
  long po = ((long)b*NN + p0 + r)*FEAT;
  #pragma unroll
  for (int e = 0; e < 2; e++){
    int f = t + e*256;
    float csum = sigm((float)fl[f])*c[cl+f] + sigm((float)fr[f])*c[cr+f];
    float cn = sigm((float)row[f])*fmaxf((float)row[2*FEAT+f], 0.f) + csum;
    float hn = sigm((float)row[FEAT+f])*tanhf(cn);
    c[po+f] = cn;
    h[po+f] = (_Float16)hn;
  }
}

// ---------------- logits[b,i] = dot(h[b,i,:], e_forw[b,:]) ----------------
__global__ void logits_kernel(const _Float16* __restrict__ h,
                              const float* __restrict__ e_forw,
                              float* __restrict__ logits){
  int b = blockIdx.y;
  int wave = threadIdx.x >> 6, lane = threadIdx.x & 63;
  int i = blockIdx.x*4 + wave;
  if (i >= NN) return;
  half8 hv = *(const half8*)(h + ((long)b*NN+i)*FEAT + lane*8);
  const float* ef = e_forw + b*FEAT + lane*8;
  float s = 0.f;
  #pragma unroll
  for (int q = 0; q < 8; q++) s += (float)hv[q]*ef[q];
  #pragma unroll
  for (int off = 32; off > 0; off >>= 1) s += __shfl_down(s, off, 64);
  if (lane == 0) logits[b*NN+i] = s;
}

// ---------------- softmax over nodes + weighted sum -> fp32 out ----------------
__global__ void out_kernel(const _Float16* __restrict__ h,
                           const float* __restrict__ logits,
                           float* __restrict__ out){
  __shared__ float sprob[NN+1];
  __shared__ float red[128];
  int b = blockIdx.x, yc = blockIdx.y, t = threadIdx.x;
  float mx = -1e30f;
  for (int i = t; i < NN; i += 128) mx = fmaxf(mx, logits[b*NN+i]);
  red[t] = mx; __syncthreads();
  for (int s = 64; s > 0; s >>= 1){ if (t < s) red[t] = fmaxf(red[t], red[t+s]); __syncthreads(); }
  mx = red[0]; __syncthreads();
  float sum = 0.f;
  for (int i = t; i < NN; i += 128){ float p = expf(logits[b*NN+i]-mx); sprob[i] = p; sum += p; }
  red[t] = sum; __syncthreads();
  for (int s = 64; s > 0; s >>= 1){ if (t < s) red[t] += red[t+s]; __syncthreads(); }
  float inv = 1.f/red[0];
  __syncthreads();
  int f = yc*128 + t;
  float acc = 0.f;
  for (int i = 0; i < NN; i++) acc += sprob[i]*(float)h[((long)b*NN+i)*FEAT+f];
  out[b*FEAT+f] = acc*inv;   // OUTPUT IS FP32
}

extern "C" void kernel_launch(void* const* d_in, const int* in_sizes, int n_in,
                              void* d_out, int out_size, void* d_ws, size_t ws_size,
                              hipStream_t stream){
  (void)in_sizes; (void)n_in; (void)out_size; (void)ws_size;
  const void* feat_raw   = d_in[0];
  const int*  finlist    = (const int*)d_in[4];
  const void* eh_raw     = d_in[5];
  const void* Wln_raw    = d_in[6];
  const void* Wlf_raw    = d_in[7];
  const void* Wiou_raw   = d_in[8];
  const void* Wfeiou_raw = d_in[9];
  const void* bfeiou_raw = d_in[10];
  const void* Wf_raw     = d_in[11];
  const void* Wfef_raw   = d_in[12];
  const void* bfef_raw   = d_in[13];

  char* ws = (char*)d_ws;
  size_t off = 0;
  auto alloc = [&](size_t bytes)->char*{
    char* p = ws + off; off += (bytes + 255) & ~(size_t)255; return p;
  };
  int*      flag     = (int*)alloc(256);
  _Float16* feat_h   = (_Float16*)alloc((size_t)NFEAT*2);
  _Float16* Wiou_h   = (_Float16*)alloc((size_t)1536*512*2);
  _Float16* Wfeiou_h = (_Float16*)alloc((size_t)1536*512*2);
  _Float16* Wf_h     = (_Float16*)alloc((size_t)512*512*2);
  _Float16* Wfef_h   = (_Float16*)alloc((size_t)512*512*2);
  _Float16* eh_h     = (_Float16*)alloc((size_t)32*1024*2);
  _Float16* Wln_h    = (_Float16*)alloc((size_t)512*1024*2);
  _Float16* Wlf_h    = (_Float16*)alloc((size_t)512*1024*2);
  float*    bfeiou_f = (float*)alloc((size_t)1536*4);
  float*    bfef_f   = (float*)alloc((size_t)512*4);
  float*    e_node   = (float*)alloc((size_t)32*512*4);
  float*    e_forw   = (float*)alloc((size_t)32*512*4);
  _Float16* feat2    = (_Float16*)alloc((size_t)NFEAT*2);
  _Float16* h_half   = (_Float16*)alloc((size_t)NFEAT*2);
  float*    c_buf    = (float*)alloc((size_t)NFEAT*4);
  _Float16* fe_iou   = (_Float16*)alloc((size_t)32*NN*1536*2);   // 50.2 MB, all nodes
  _Float16* fe_f     = (_Float16*)alloc((size_t)32*255*512*2);   // 8.4 MB, all parents
  _Float16* f_buf    = (_Float16*)alloc((size_t)32*256*512*2);
  float*    logits   = (float*)alloc((size_t)32*NN*4);

  detect_kernel<<<dim3(1), 256, 0, stream>>>((const unsigned short*)feat_raw, flag);

  cvt_all<<<dim3(5641), 256, 0, stream>>>(
      feat_raw, Wiou_raw, Wfeiou_raw, Wf_raw, Wfef_raw, eh_raw, Wln_raw, Wlf_raw,
      bfeiou_raw, bfef_raw,
      feat_h, Wiou_h, Wfeiou_h, Wf_h, Wfef_h, eh_h, Wln_h, Wlf_h,
      bfeiou_f, bfef_f, flag);

  e_mfma<<<dim3(64), 64, 0, stream>>>(eh_h, Wln_h, Wlf_h, e_node, e_forw);
  feat2_kernel<<<dim3(NN,32), 256, 0, stream>>>(feat_h, finlist, e_node, feat2);

  // one giant h-independent precompute: 256 row tiles x 32 col groups = 8192 blocks
  gemm_pre<<<dim3(256, 32), 64, 0, stream>>>(
      feat2, Wfeiou_h, Wfef_h, bfeiou_f, bfef_f, fe_iou, fe_f);

  // leaf level: no GEMM needed
  pw_leaf<<<dim3(256,32), 256, 0, stream>>>(fe_iou, c_buf, h_half);

  for (int n = 1; n <= 8; n++){
    int P = 1 << (8-n);
    int lp = 8 - n;
    int p0 = P - 1, c0 = 2*P - 1;
    gemm_lvl<<<dim3(P, 32), 64, 0, stream>>>(P, lp,
        h_half, Wiou_h, Wf_h, fe_iou, fe_f, f_buf);
    pw_level<<<dim3(P,32), 256, 0, stream>>>(fe_iou, f_buf, c_buf, h_half, P, p0, c0);
  }

  logits_kernel<<<dim3(128,32), 256, 0, stream>>>(h_half, e_forw, logits);
  out_kernel<<<dim3(32,4), 128, 0, stream>>>(h_half, logits, (float*)d_out);
}